// Round 11
// baseline (282.893 us; speedup 1.0000x reference)
//
#include <hip/hip_runtime.h>

#define NB 8
#define NN 1024
#define NH 8
#define HD 96
#define DIM 768

typedef __bf16 bf16x8 __attribute__((ext_vector_type(8)));
typedef float f32x4 __attribute__((ext_vector_type(4)));
typedef unsigned short u16x8 __attribute__((ext_vector_type(8)));
typedef _Float16 half8 __attribute__((ext_vector_type(8)));

__device__ __forceinline__ ushort f2bf(float f) {
  uint u = __float_as_uint(f);
  u += 0x7fffu + ((u >> 16) & 1u);
  return (ushort)(u >> 16);
}
__device__ __forceinline__ float bf2f(ushort u) {
  return __uint_as_float(((uint)u) << 16);
}
__device__ __forceinline__ ushort f2h(float f) {
  union { _Float16 h; ushort u; } c;
  c.h = (_Float16)f;
  return c.u;
}

// ---------------- K0b: proj_w [768][768] f32 -> wT bf16 [j][d] ----------------
__global__ __launch_bounds__(256) void k_prep_w(const float* __restrict__ pw,
                                                ushort* __restrict__ wT) {
  __shared__ ushort tile[64][72];
  int d0 = blockIdx.x * 64;
  int j0 = blockIdx.y * 64;
  int t = threadIdx.x;
  {
    int r = t >> 2;
    int ch = (t & 3) * 16;
    const float* src = pw + (size_t)(d0 + r) * DIM + j0 + ch;
#pragma unroll
    for (int i = 0; i < 16; i += 4) {
      float4 v = *(const float4*)(src + i);
      tile[ch + i + 0][r] = f2bf(v.x);
      tile[ch + i + 1][r] = f2bf(v.y);
      tile[ch + i + 2][r] = f2bf(v.z);
      tile[ch + i + 3][r] = f2bf(v.w);
    }
  }
  __syncthreads();
  {
    int j = t >> 2;
    int ch = (t & 3) * 16;
    union { ushort u[16]; uint4 v[2]; } tmp;
#pragma unroll
    for (int i = 0; i < 16; ++i) tmp.u[i] = tile[j][ch + i];
    uint4* dst = (uint4*)(wT + (size_t)(j0 + j) * DIM + d0 + ch);
    dst[0] = tmp.v[0]; dst[1] = tmp.v[1];
  }
}

// ---------------- K1: 3x3 SAME conv per 16x16x3 token image -> q bf16 ----------------
__global__ __launch_bounds__(256) void k_conv(const float* __restrict__ x,
                                              const float* __restrict__ w,
                                              ushort* __restrict__ q) {
  __shared__ float xs[768];
  __shared__ float ws[81];
  __shared__ ushort os[768];
  int token = blockIdx.x;
  int t = threadIdx.x;
  const float4* xin = (const float4*)(x + (size_t)token * DIM);
  if (t < 192) ((float4*)xs)[t] = xin[t];
  if (t < 81) ws[t] = w[t];
  __syncthreads();
  int r = t >> 4, c = t & 15;
  float a0 = 0.f, a1 = 0.f, a2 = 0.f;
#pragma unroll
  for (int dr = 0; dr < 3; ++dr) {
    int rr = r + dr - 1;
    bool rok = (rr >= 0) & (rr < 16);
#pragma unroll
    for (int dc = 0; dc < 3; ++dc) {
      int cc = c + dc - 1;
      bool ok = rok & (cc >= 0) & (cc < 16);
#pragma unroll
      for (int ci = 0; ci < 3; ++ci) {
        int idx = ok ? (rr * 16 + cc) * 3 + ci : 0;
        float xv = xs[idx];
        xv = ok ? xv : 0.f;
        const float* wp = ws + ((dr * 3 + dc) * 3 + ci) * 3;
        a0 += xv * wp[0]; a1 += xv * wp[1]; a2 += xv * wp[2];
      }
    }
  }
  os[t * 3 + 0] = f2bf(a0);
  os[t * 3 + 1] = f2bf(a1);
  os[t * 3 + 2] = f2bf(a2);
  __syncthreads();
  uint4* dst = (uint4*)(q + (size_t)token * DIM);
  if (t < 96) dst[t] = ((const uint4*)os)[t];
}

// ---------------- K1b: q [b][n][d] -> qT [b][d][n] (bf16) ----------------
__global__ __launch_bounds__(256) void k_transpose_q(const ushort* __restrict__ q,
                                                     ushort* __restrict__ qT) {
  __shared__ ushort tile[64][72];
  int bb = blockIdx.z;
  int n0 = blockIdx.x * 64;
  int d0 = blockIdx.y * 64;
  int t = threadIdx.x;
  {
    int r = t >> 2;
    int cq = (t & 3) * 16;
    const ushort* src = q + ((size_t)(bb * NN) + n0 + r) * DIM + d0 + cq;
    uint4 v0 = *(const uint4*)src;
    uint4 v1 = *(const uint4*)(src + 8);
    *(uint4*)&tile[r][cq] = v0;
    *(uint4*)&tile[r][cq + 8] = v1;
  }
  __syncthreads();
  {
    int d = t >> 2;
    int nch = (t & 3) * 16;
    union { ushort u[16]; uint4 v[2]; } tmp;
#pragma unroll
    for (int j = 0; j < 16; ++j) tmp.u[j] = tile[nch + j][d];
    uint4* dst = (uint4*)(qT + ((size_t)(bb * DIM) + d0 + d) * NN + n0 + nch);
    dst[0] = tmp.v[0]; dst[1] = tmp.v[1];
  }
}

// ---------------- K2: p = exp(scale * q_h q_h^T) fp16, + per-colblock row psums ------
// 128x128 tile GEMM (round-8 version: direct scalar stores; L2 merges them).
__global__ __launch_bounds__(256) void k_qk(const ushort* __restrict__ q,
                                            ushort* __restrict__ p,
                                            float* __restrict__ psum, int b0) {
  __shared__ ushort As[128][104];
  __shared__ ushort Bs[128][104];
  __shared__ float rsum_l[128][2];
  int z = blockIdx.z;
  int bc = z >> 3, h = z & 7;
  int bb = b0 + bc;
  int r0 = blockIdx.x * 128;  // n rows
  int c0 = blockIdx.y * 128;  // m cols
  int t = threadIdx.x;
  const ushort* qb = q + (size_t)bb * NN * DIM + h * HD;
  for (int i = t; i < 1536; i += 256) {
    int row = i / 12;
    int ck = (i % 12) * 8;
    *(uint4*)&As[row][ck] = *(const uint4*)(qb + (size_t)(r0 + row) * DIM + ck);
    *(uint4*)&Bs[row][ck] = *(const uint4*)(qb + (size_t)(c0 + row) * DIM + ck);
  }
  __syncthreads();
  int wv = t >> 6, lane = t & 63;
  int wr = (wv >> 1) * 64, wc = (wv & 1) * 64;
  int lm = lane & 15, lg = lane >> 4;
  f32x4 acc[4][4] = {};
#pragma unroll
  for (int ks = 0; ks < 3; ++ks) {
    bf16x8 af[4], bfr[4];
#pragma unroll
    for (int mi = 0; mi < 4; ++mi)
      af[mi] = *(const bf16x8*)&As[wr + mi * 16 + lm][ks * 32 + lg * 8];
#pragma unroll
    for (int ni = 0; ni < 4; ++ni)
      bfr[ni] = *(const bf16x8*)&Bs[wc + ni * 16 + lm][ks * 32 + lg * 8];
#pragma unroll
    for (int mi = 0; mi < 4; ++mi)
#pragma unroll
      for (int ni = 0; ni < 4; ++ni)
        acc[mi][ni] = __builtin_amdgcn_mfma_f32_16x16x32_bf16(af[mi], bfr[ni], acc[mi][ni], 0, 0, 0);
  }
  const float scale = 0.10206207261596575f;  // 96^-0.5
  ushort* pb = p + (size_t)(bc * 8 + h) * NN * NN;
  float rsum[4][4] = {};
#pragma unroll
  for (int mi = 0; mi < 4; ++mi)
#pragma unroll
    for (int ni = 0; ni < 4; ++ni)
#pragma unroll
      for (int r = 0; r < 4; ++r) {
        float e = __expf(acc[mi][ni][r] * scale);
        int row = r0 + wr + mi * 16 + lg * 4 + r;
        int col = c0 + wc + ni * 16 + lm;
        pb[(size_t)row * NN + col] = f2h(e);
        rsum[mi][r] += e;
      }
#pragma unroll
  for (int mi = 0; mi < 4; ++mi)
#pragma unroll
    for (int r = 0; r < 4; ++r) {
      float s = rsum[mi][r];
      s += __shfl_xor(s, 1); s += __shfl_xor(s, 2);
      s += __shfl_xor(s, 4); s += __shfl_xor(s, 8);
      if (lm == 0) rsum_l[wr + mi * 16 + lg * 4 + r][wv & 1] = s;
    }
  __syncthreads();
  if (t < 128)
    psum[((size_t)(bc * 8 + h) * 8 + blockIdx.y) * NN + r0 + t] =
        rsum_l[t][0] + rsum_l[t][1];
}

// ---------------- K3: invb[b0*8+bhc][n] = 1 / sum_cb psum[bhc][cb][n] ----------------
__global__ __launch_bounds__(256) void k_inv(const float* __restrict__ psum,
                                             float* __restrict__ invb, int b0) {
  int gi = blockIdx.x * 256 + threadIdx.x;
  int bhc = gi >> 10, n = gi & 1023;
  float s = 0.f;
#pragma unroll
  for (int cb = 0; cb < 8; ++cb) s += psum[((size_t)bhc * 8 + cb) * NN + n];
  invb[(size_t)(b0 * 8 + bhc) * NN + n] = 1.f / s;
}

// ---------------- K4: stage p -> normalize+mix+BN -> attn write + PV MFMA ----------
// m-range SPLIT across 2 blocks (mh) -> grid doubles -> 4 blocks/CU resident.
// PV partials via unsafeAtomicAdd into pacc: exactly 2 commutative f32 contributions
// per cell from memset-0 -> bitwise deterministic. P double-buffered 2x16KB.
__global__ __launch_bounds__(512, 4) void k_mixpv(
    const ushort* __restrict__ p, const ushort* __restrict__ qT,
    const float* __restrict__ invb, const float* __restrict__ rw,
    const float* __restrict__ rb, const float* __restrict__ gamma,
    const float* __restrict__ beta, const float* __restrict__ mean,
    const float* __restrict__ var,
    float* __restrict__ attn, float* __restrict__ pacc,
    int b0, int bmask, int bshift) {
  __shared__ char P[2][16384];  // [2][8h][16n][64m] fp16, XOR-swizzled rows

  const int lin = blockIdx.x;
  const int bc = lin & bmask;      // chunk-local batch (XCD locality in full mode)
  const int bb = b0 + bc;
  const int rest = lin >> bshift;
  const int nt = rest >> 1;        // 0..63
  const int mh = rest & 1;         // m half
  const int n0 = nt * 16;
  const int mbase = mh * 512;
  const int t = threadIdx.x;
  const int w = t >> 6, lane = t & 63;
  const int lm = lane & 15, lg = lane >> 4;

  // per-lane fold: coef[h] = w[h][g=w] * inv[h][n=lm]
  float coef[8];
#pragma unroll
  for (int h = 0; h < 8; ++h)
    coef[h] = rw[h * 8 + w] * invb[(size_t)(bb * 8 + h) * NN + n0 + lm];
  const float effs = gamma[w] * __frsqrt_rn(var[w] + 1e-3f);
  const float effb = (rb[w] - mean[w]) * effs + beta[w];

  const ushort* pb = p + (size_t)bc * 8 * NN * NN;
  const ushort* vb = qT + (size_t)bb * DIM * NN;

  // staging map: thread t -> row srow=t>>2 (h=srow>>4, n=srow&15), 32B quarter q4=t&3
  const int srow = t >> 2, q4 = t & 3;
  const int sh_ = srow >> 4, sn = srow & 15;
  const int swz_s = (sn & 7) << 4;
  const ushort* psrc = pb + ((size_t)(sh_ * NN) + n0 + sn) * NN + mbase + q4 * 16;

  f32x4 oacc[6] = {};

  // prologue: stage mt=0
  {
    uint4 u0 = *(const uint4*)(psrc);
    uint4 u1 = *(const uint4*)(psrc + 8);
    char* base = P[0] + srow * 128;
    *(uint4*)(base + ((q4 * 32) ^ swz_s)) = u0;
    *(uint4*)(base + ((q4 * 32 + 16) ^ swz_s)) = u1;
  }
  __syncthreads();

  for (int mt = 0; mt < 8; ++mt) {
    // stage next chunk into the other buffer (overlaps with compute below)
    if (mt < 7) {
      const ushort* sp = psrc + (mt + 1) * 64;
      uint4 u0 = *(const uint4*)(sp);
      uint4 u1 = *(const uint4*)(sp + 8);
      char* base = P[(mt + 1) & 1] + srow * 128;
      *(uint4*)(base + ((q4 * 32) ^ swz_s)) = u0;
      *(uint4*)(base + ((q4 * 32 + 16) ^ swz_s)) = u1;
    }
    const char* Pc = P[mt & 1];
    const int m0 = mbase + mt * 64;
#pragma unroll
    for (int ks = 0; ks < 2; ++ks) {
      float mix[8];
#pragma unroll
      for (int j = 0; j < 8; ++j) mix[j] = 0.f;
      const int cb = (ks * 64 + lg * 16) ^ ((lm & 7) << 4);
#pragma unroll
      for (int h = 0; h < 8; ++h) {
        union { u16x8 u; half8 hh; } pu;
        pu.u = *(const u16x8*)(Pc + (h * 16 + lm) * 128 + cb);
        float c = coef[h];
#pragma unroll
        for (int j = 0; j < 8; ++j) mix[j] += (float)pu.hh[j] * c;
      }
      f32x4 o0, o1;
#pragma unroll
      for (int j = 0; j < 4; ++j) o0[j] = mix[j] * effs + effb;
#pragma unroll
      for (int j = 0; j < 4; ++j) o1[j] = mix[4 + j] * effs + effb;
      size_t arow = ((size_t)(bb * 8 + w) * NN + (n0 + lm)) * NN + m0 + ks * 32 + lg * 8;
      __builtin_nontemporal_store(o0, (f32x4*)(attn + arow));
      __builtin_nontemporal_store(o1, (f32x4*)(attn + arow + 4));
      // pack POST-BN values as PV A-frag
      u16x8 pk;
#pragma unroll
      for (int j = 0; j < 4; ++j) pk[j] = f2bf(o0[j]);
#pragma unroll
      for (int j = 0; j < 4; ++j) pk[4 + j] = f2bf(o1[j]);
      bf16x8 pmf = *(bf16x8*)&pk;
      bf16x8 vf[6];
#pragma unroll
      for (int df = 0; df < 6; ++df)
        vf[df] = *(const bf16x8*)(vb + (size_t)(w * HD + df * 16 + lm) * NN
                                   + m0 + ks * 32 + lg * 8);
#pragma unroll
      for (int df = 0; df < 6; ++df)
        oacc[df] = __builtin_amdgcn_mfma_f32_16x16x32_bf16(pmf, vf[df], oacc[df], 0, 0, 0);
    }
    __syncthreads();
  }

  // epilogue: atomic PV partial (2 contributions/cell, commutative -> deterministic)
#pragma unroll
  for (int df = 0; df < 6; ++df) {
    int col = w * HD + df * 16 + lm;
#pragma unroll
    for (int r = 0; r < 4; ++r) {
      int row = n0 + lg * 4 + r;
      unsafeAtomicAdd(&pacc[(size_t)(bc * NN + row) * DIM + col], oacc[df][r]);
    }
  }
}

// ---------------- K4b: outb = bf16(pacc) (post-BN PV needs no affine fix) ----------
__global__ __launch_bounds__(256) void k_sumfix(const float* __restrict__ pacc,
                                                ushort* __restrict__ outb) {
  size_t base = ((size_t)blockIdx.x * 256 + threadIdx.x) * 4;
  f32x4 v = *(const f32x4*)(pacc + base);
  ushort4 o;
  o.x = f2bf(v[0]); o.y = f2bf(v[1]); o.z = f2bf(v[2]); o.w = f2bf(v[3]);
  *(ushort4*)(outb + base) = o;
}

// ---------------- K6: xo = out @ proj_w + proj_b (bf16 MFMA, fp32 out) ----------------
__global__ __launch_bounds__(256) void k_proj(const ushort* __restrict__ outb,
                                              const ushort* __restrict__ wT,
                                              const float* __restrict__ pb,
                                              float* __restrict__ xo) {
  __shared__ ushort As[128][72];
  __shared__ ushort Bs[128][72];
  int m0 = blockIdx.x * 128;
  int j0 = blockIdx.y * 128;
  int t = threadIdx.x;
  int wv = t >> 6, lane = t & 63;
  int wr = (wv >> 1) * 64, wc = (wv & 1) * 64;
  int lm = lane & 15, lg = lane >> 4;
  f32x4 acc[4][4] = {};
  for (int kk = 0; kk < 12; ++kk) {
    int k0 = kk * 64;
    __syncthreads();
    for (int i = t; i < 1024; i += 256) {
      int row = i >> 3;
      int c = (i & 7) * 8;
      *(uint4*)&As[row][c] = *(const uint4*)(outb + (size_t)(m0 + row) * DIM + k0 + c);
      *(uint4*)&Bs[row][c] = *(const uint4*)(wT + (size_t)(j0 + row) * DIM + k0 + c);
    }
    __syncthreads();
#pragma unroll
    for (int ks = 0; ks < 2; ++ks) {
      bf16x8 af[4], bfr[4];
#pragma unroll
      for (int mi = 0; mi < 4; ++mi)
        af[mi] = *(const bf16x8*)&As[wr + mi * 16 + lm][ks * 32 + lg * 8];
#pragma unroll
      for (int ni = 0; ni < 4; ++ni)
        bfr[ni] = *(const bf16x8*)&Bs[wc + ni * 16 + lm][ks * 32 + lg * 8];
#pragma unroll
      for (int mi = 0; mi < 4; ++mi)
#pragma unroll
        for (int ni = 0; ni < 4; ++ni)
          acc[mi][ni] = __builtin_amdgcn_mfma_f32_16x16x32_bf16(af[mi], bfr[ni], acc[mi][ni], 0, 0, 0);
    }
  }
#pragma unroll
  for (int ni = 0; ni < 4; ++ni) {
    int col = j0 + wc + ni * 16 + lm;
    float bias = pb[col];
#pragma unroll
    for (int mi = 0; mi < 4; ++mi)
#pragma unroll
      for (int r = 0; r < 4; ++r) {
        int row = m0 + wr + mi * 16 + lg * 4 + r;
        xo[(size_t)row * DIM + col] = acc[mi][ni][r] + bias;
      }
  }
}

extern "C" void kernel_launch(void* const* d_in, const int* in_sizes, int n_in,
                              void* d_out, int out_size, void* d_ws, size_t ws_size,
                              hipStream_t stream) {
  (void)in_sizes; (void)n_in; (void)out_size;
  const float* x       = (const float*)d_in[0];
  const float* qconv_w = (const float*)d_in[1];
  const float* rw      = (const float*)d_in[2];
  const float* rb      = (const float*)d_in[3];
  const float* gamma   = (const float*)d_in[4];
  const float* beta    = (const float*)d_in[5];
  const float* mean    = (const float*)d_in[6];
  const float* var     = (const float*)d_in[7];
  const float* pw      = (const float*)d_in[8];
  const float* pb      = (const float*)d_in[9];

  float* xo   = (float*)d_out;
  float* attn = xo + (size_t)NB * NN * DIM;  // attn_next output region

  char* ws = (char*)d_ws;
  ushort* q    = (ushort*)(ws);                 // 12,582,912 B
  ushort* qT   = (ushort*)(ws + 12582912);      // 12,582,912 B
  ushort* wT   = (ushort*)(ws + 25165824);      //  1,179,648 B
  ushort* outb = (ushort*)(ws + 26345472);      // 12,582,912 B
  float*  invb = (float*)(ws + 38928384);       //    262,144 B
  float*  psum = (float*)(ws + 39190528);       //  2,097,152 B (max)
  float*  pacc = (float*)(ws + 41287680);       // full: 25,165,824 B; chunk: 3,145,728 B
  // p follows pacc
  hipLaunchKernelGGL(k_prep_w, dim3(12, 12), dim3(256), 0, stream, pw, wT);
  hipLaunchKernelGGL(k_conv, dim3(NB * NN), dim3(256), 0, stream, x, qconv_w, q);
  hipLaunchKernelGGL(k_transpose_q, dim3(16, 12, NB), dim3(256), 0, stream, q, qT);

  if (ws_size >= 200671232ull) {
    // full mode: all 8 batches at once
    ushort* p = (ushort*)(ws + 66453504);       // 134,217,728 B
    hipMemsetAsync(pacc, 0, (size_t)NB * NN * DIM * sizeof(float), stream);
    hipLaunchKernelGGL(k_qk, dim3(8, 8, 64), dim3(256), 0, stream, q, p, psum, 0);
    hipLaunchKernelGGL(k_inv, dim3(256), dim3(256), 0, stream, psum, invb, 0);
    hipLaunchKernelGGL(k_mixpv, dim3(1024), dim3(512), 0, stream, p, qT, invb,
                       rw, rb, gamma, beta, mean, var, attn, pacc, 0, 7, 3);
    hipLaunchKernelGGL(k_sumfix, dim3(6144), dim3(256), 0, stream, pacc, outb);
  } else {
    // chunked fallback: one batch at a time (p/pacc slabs reused; ~61 MB total ws)
    ushort* p = (ushort*)(ws + 44433408);       // 16,777,216 B
    for (int c = 0; c < NB; ++c) {
      hipMemsetAsync(pacc, 0, (size_t)NN * DIM * sizeof(float), stream);
      hipLaunchKernelGGL(k_qk, dim3(8, 8, 8), dim3(256), 0, stream, q, p, psum, c);
      hipLaunchKernelGGL(k_inv, dim3(32), dim3(256), 0, stream, psum, invb, c);
      hipLaunchKernelGGL(k_mixpv, dim3(128), dim3(512), 0, stream, p, qT, invb,
                         rw, rb, gamma, beta, mean, var, attn, pacc, c, 0, 0);
      hipLaunchKernelGGL(k_sumfix, dim3(768), dim3(256), 0, stream, pacc,
                         outb + (size_t)c * NN * DIM);
    }
  }
  hipLaunchKernelGGL(k_proj, dim3(64, 6), dim3(256), 0, stream, outb, wT, pb, xo);
}

// Round 12
// 252.427 us; speedup vs baseline: 1.1207x; 1.1207x over previous
//
#include <hip/hip_runtime.h>

#define NB 8
#define NN 1024
#define NH 8
#define HD 96
#define DIM 768

typedef __bf16 bf16x8 __attribute__((ext_vector_type(8)));
typedef float f32x4 __attribute__((ext_vector_type(4)));
typedef unsigned short u16x8 __attribute__((ext_vector_type(8)));
typedef _Float16 half8 __attribute__((ext_vector_type(8)));

__device__ __forceinline__ ushort f2bf(float f) {
  uint u = __float_as_uint(f);
  u += 0x7fffu + ((u >> 16) & 1u);
  return (ushort)(u >> 16);
}
__device__ __forceinline__ float bf2f(ushort u) {
  return __uint_as_float(((uint)u) << 16);
}
__device__ __forceinline__ ushort f2h(float f) {
  union { _Float16 h; ushort u; } c;
  c.h = (_Float16)f;
  return c.u;
}

// ---------------- K0b: proj_w [768][768] f32 -> wT bf16 [j][d] ----------------
__global__ __launch_bounds__(256) void k_prep_w(const float* __restrict__ pw,
                                                ushort* __restrict__ wT) {
  __shared__ ushort tile[64][72];
  int d0 = blockIdx.x * 64;
  int j0 = blockIdx.y * 64;
  int t = threadIdx.x;
  {
    int r = t >> 2;
    int ch = (t & 3) * 16;
    const float* src = pw + (size_t)(d0 + r) * DIM + j0 + ch;
#pragma unroll
    for (int i = 0; i < 16; i += 4) {
      float4 v = *(const float4*)(src + i);
      tile[ch + i + 0][r] = f2bf(v.x);
      tile[ch + i + 1][r] = f2bf(v.y);
      tile[ch + i + 2][r] = f2bf(v.z);
      tile[ch + i + 3][r] = f2bf(v.w);
    }
  }
  __syncthreads();
  {
    int j = t >> 2;
    int ch = (t & 3) * 16;
    union { ushort u[16]; uint4 v[2]; } tmp;
#pragma unroll
    for (int i = 0; i < 16; ++i) tmp.u[i] = tile[j][ch + i];
    uint4* dst = (uint4*)(wT + (size_t)(j0 + j) * DIM + d0 + ch);
    dst[0] = tmp.v[0]; dst[1] = tmp.v[1];
  }
}

// ---------------- K1: 3x3 SAME conv per 16x16x3 token image -> q bf16 ----------------
__global__ __launch_bounds__(256) void k_conv(const float* __restrict__ x,
                                              const float* __restrict__ w,
                                              ushort* __restrict__ q) {
  __shared__ float xs[768];
  __shared__ float ws[81];
  __shared__ ushort os[768];
  int token = blockIdx.x;
  int t = threadIdx.x;
  const float4* xin = (const float4*)(x + (size_t)token * DIM);
  if (t < 192) ((float4*)xs)[t] = xin[t];
  if (t < 81) ws[t] = w[t];
  __syncthreads();
  int r = t >> 4, c = t & 15;
  float a0 = 0.f, a1 = 0.f, a2 = 0.f;
#pragma unroll
  for (int dr = 0; dr < 3; ++dr) {
    int rr = r + dr - 1;
    bool rok = (rr >= 0) & (rr < 16);
#pragma unroll
    for (int dc = 0; dc < 3; ++dc) {
      int cc = c + dc - 1;
      bool ok = rok & (cc >= 0) & (cc < 16);
#pragma unroll
      for (int ci = 0; ci < 3; ++ci) {
        int idx = ok ? (rr * 16 + cc) * 3 + ci : 0;
        float xv = xs[idx];
        xv = ok ? xv : 0.f;
        const float* wp = ws + ((dr * 3 + dc) * 3 + ci) * 3;
        a0 += xv * wp[0]; a1 += xv * wp[1]; a2 += xv * wp[2];
      }
    }
  }
  os[t * 3 + 0] = f2bf(a0);
  os[t * 3 + 1] = f2bf(a1);
  os[t * 3 + 2] = f2bf(a2);
  __syncthreads();
  uint4* dst = (uint4*)(q + (size_t)token * DIM);
  if (t < 96) dst[t] = ((const uint4*)os)[t];
}

// ---------------- K1b: q [b][n][d] -> qT [b][d][n] (bf16) ----------------
__global__ __launch_bounds__(256) void k_transpose_q(const ushort* __restrict__ q,
                                                     ushort* __restrict__ qT) {
  __shared__ ushort tile[64][72];
  int bb = blockIdx.z;
  int n0 = blockIdx.x * 64;
  int d0 = blockIdx.y * 64;
  int t = threadIdx.x;
  {
    int r = t >> 2;
    int cq = (t & 3) * 16;
    const ushort* src = q + ((size_t)(bb * NN) + n0 + r) * DIM + d0 + cq;
    uint4 v0 = *(const uint4*)src;
    uint4 v1 = *(const uint4*)(src + 8);
    *(uint4*)&tile[r][cq] = v0;
    *(uint4*)&tile[r][cq + 8] = v1;
  }
  __syncthreads();
  {
    int d = t >> 2;
    int nch = (t & 3) * 16;
    union { ushort u[16]; uint4 v[2]; } tmp;
#pragma unroll
    for (int j = 0; j < 16; ++j) tmp.u[j] = tile[nch + j][d];
    uint4* dst = (uint4*)(qT + ((size_t)(bb * DIM) + d0 + d) * NN + n0 + nch);
    dst[0] = tmp.v[0]; dst[1] = tmp.v[1];
  }
}

// ---------------- K2: p = exp(scale * q_h q_h^T) fp16, + per-wave row psums ------
// 128x128 tile GEMM (round-8 store path). Wave-direct psum partials: NO second
// barrier, no rsum_l LDS. psum slot = ((bh*8+by)*2 + wave-col-half); k_inv sums 16.
__global__ __launch_bounds__(256) void k_qk(const ushort* __restrict__ q,
                                            ushort* __restrict__ p,
                                            float* __restrict__ psum, int b0) {
  __shared__ ushort As[128][104];
  __shared__ ushort Bs[128][104];
  int z = blockIdx.z;
  int bc = z >> 3, h = z & 7;
  int bb = b0 + bc;
  int r0 = blockIdx.x * 128;  // n rows
  int c0 = blockIdx.y * 128;  // m cols
  int t = threadIdx.x;
  const ushort* qb = q + (size_t)bb * NN * DIM + h * HD;
  for (int i = t; i < 1536; i += 256) {
    int row = i / 12;
    int ck = (i % 12) * 8;
    *(uint4*)&As[row][ck] = *(const uint4*)(qb + (size_t)(r0 + row) * DIM + ck);
    *(uint4*)&Bs[row][ck] = *(const uint4*)(qb + (size_t)(c0 + row) * DIM + ck);
  }
  __syncthreads();
  int wv = t >> 6, lane = t & 63;
  int wr = (wv >> 1) * 64, wc = (wv & 1) * 64;
  int lm = lane & 15, lg = lane >> 4;
  f32x4 acc[4][4] = {};
#pragma unroll
  for (int ks = 0; ks < 3; ++ks) {
    bf16x8 af[4], bfr[4];
#pragma unroll
    for (int mi = 0; mi < 4; ++mi)
      af[mi] = *(const bf16x8*)&As[wr + mi * 16 + lm][ks * 32 + lg * 8];
#pragma unroll
    for (int ni = 0; ni < 4; ++ni)
      bfr[ni] = *(const bf16x8*)&Bs[wc + ni * 16 + lm][ks * 32 + lg * 8];
#pragma unroll
    for (int mi = 0; mi < 4; ++mi)
#pragma unroll
      for (int ni = 0; ni < 4; ++ni)
        acc[mi][ni] = __builtin_amdgcn_mfma_f32_16x16x32_bf16(af[mi], bfr[ni], acc[mi][ni], 0, 0, 0);
  }
  const float scale = 0.10206207261596575f;  // 96^-0.5
  ushort* pb = p + (size_t)(bc * 8 + h) * NN * NN;
  float rsum[4][4] = {};
#pragma unroll
  for (int mi = 0; mi < 4; ++mi)
#pragma unroll
    for (int ni = 0; ni < 4; ++ni)
#pragma unroll
      for (int r = 0; r < 4; ++r) {
        float e = __expf(acc[mi][ni][r] * scale);
        int row = r0 + wr + mi * 16 + lg * 4 + r;
        int col = c0 + wc + ni * 16 + lm;
        pb[(size_t)row * NN + col] = f2h(e);
        rsum[mi][r] += e;
      }
  // wave-direct partial rowsums: slot = (bh*8+by)*2 + (wv&1); rows wr..wr+63
  float* ps = psum + ((size_t)((bc * 8 + h) * 8 + blockIdx.y) * 2 + (wv & 1)) * NN + r0;
#pragma unroll
  for (int mi = 0; mi < 4; ++mi)
#pragma unroll
    for (int r = 0; r < 4; ++r) {
      float s = rsum[mi][r];
      s += __shfl_xor(s, 1); s += __shfl_xor(s, 2);
      s += __shfl_xor(s, 4); s += __shfl_xor(s, 8);
      if (lm == 0) ps[wr + mi * 16 + lg * 4 + r] = s;
    }
}

// ---------------- K3: invb[b0*8+bhc][n] = 1 / sum_cb psum[bhc][cb][n], cb<16 ------
__global__ __launch_bounds__(256) void k_inv(const float* __restrict__ psum,
                                             float* __restrict__ invb, int b0) {
  int gi = blockIdx.x * 256 + threadIdx.x;
  int bhc = gi >> 10, n = gi & 1023;
  float s = 0.f;
#pragma unroll
  for (int cb = 0; cb < 16; ++cb) s += psum[((size_t)bhc * 16 + cb) * NN + n];
  invb[(size_t)(b0 * 8 + bhc) * NN + n] = 1.f / s;
}

// ---------------- K4: stage p -> normalize+mix+BN -> attn write + PV MFMA ----------
// 512 thr = 8 waves; wave w = output channel g. Block = (bc, 16-row n-tile).
// BK=128: P buffers 2x32KB ([8h][16n][128m] fp16), mt loop 8 iters -> HALF the
// barriers of round 8. Staging 4x uint4/thread. XOR swizzle on 16B slots.
__global__ __launch_bounds__(512, 4) void k_mixpv(
    const ushort* __restrict__ p, const ushort* __restrict__ qT,
    const float* __restrict__ invb, const float* __restrict__ rw,
    const float* __restrict__ rb, const float* __restrict__ gamma,
    const float* __restrict__ beta, const float* __restrict__ mean,
    const float* __restrict__ var,
    float* __restrict__ attn, ushort* __restrict__ outb,
    int b0, int bmask, int bshift) {
  __shared__ char P[2][32768];  // [2][8h][16n][128m] fp16, XOR-swizzled rows (256B)

  const int lin = blockIdx.x;
  const int bc = lin & bmask;
  const int bb = b0 + bc;
  const int nt = lin >> bshift;
  const int n0 = nt * 16;
  const int t = threadIdx.x;
  const int w = t >> 6, lane = t & 63;
  const int lm = lane & 15, lg = lane >> 4;

  // per-lane fold: coef[h] = w[h][g=w] * inv[h][n=lm]
  float coef[8];
#pragma unroll
  for (int h = 0; h < 8; ++h)
    coef[h] = rw[h * 8 + w] * invb[(size_t)(bb * 8 + h) * NN + n0 + lm];
  const float effs = gamma[w] * __frsqrt_rn(var[w] + 1e-3f);
  const float effb = (rb[w] - mean[w]) * effs + beta[w];

  const ushort* pb = p + (size_t)bc * 8 * NN * NN;
  const ushort* vb = qT + (size_t)bb * DIM * NN;

  // staging map: thread t -> row srow=t>>2 (h=srow>>4, n=srow&15), 64B quarter q4=t&3
  const int srow = t >> 2, q4 = t & 3;
  const int sh_ = srow >> 4, sn = srow & 15;
  const int swz_s = (sn & 7) << 4;
  const ushort* psrc = pb + ((size_t)(sh_ * NN) + n0 + sn) * NN + q4 * 32;

  f32x4 oacc[6] = {};

  // prologue: stage mt=0 (128 cols)
  {
    char* base = P[0] + srow * 256;
#pragma unroll
    for (int i = 0; i < 4; ++i) {
      uint4 u = *(const uint4*)(psrc + i * 8);
      *(uint4*)(base + ((q4 * 64 + i * 16) ^ swz_s)) = u;
    }
  }
  __syncthreads();

  for (int mt = 0; mt < 8; ++mt) {
    // stage next 128-col chunk into the other buffer (overlaps with compute below)
    if (mt < 7) {
      const ushort* sp = psrc + (mt + 1) * 128;
      char* base = P[(mt + 1) & 1] + srow * 256;
#pragma unroll
      for (int i = 0; i < 4; ++i) {
        uint4 u = *(const uint4*)(sp + i * 8);
        *(uint4*)(base + ((q4 * 64 + i * 16) ^ swz_s)) = u;
      }
    }
    const char* Pc = P[mt & 1];
    const int m0 = mt * 128;
#pragma unroll
    for (int ks = 0; ks < 4; ++ks) {
      float mix[8];
#pragma unroll
      for (int j = 0; j < 8; ++j) mix[j] = 0.f;
      const int cb = (ks * 32 + lg * 8) * 2;
      const int cbs = cb ^ ((lm & 7) << 4);
#pragma unroll
      for (int h = 0; h < 8; ++h) {
        union { u16x8 u; half8 hh; } pu;
        pu.u = *(const u16x8*)(Pc + (h * 16 + lm) * 256 + cbs);
        float c = coef[h];
#pragma unroll
        for (int j = 0; j < 8; ++j) mix[j] += (float)pu.hh[j] * c;
      }
      f32x4 o0, o1;
#pragma unroll
      for (int j = 0; j < 4; ++j) o0[j] = mix[j] * effs + effb;
#pragma unroll
      for (int j = 0; j < 4; ++j) o1[j] = mix[4 + j] * effs + effb;
      size_t arow = ((size_t)(bb * 8 + w) * NN + (n0 + lm)) * NN + m0 + ks * 32 + lg * 8;
      __builtin_nontemporal_store(o0, (f32x4*)(attn + arow));
      __builtin_nontemporal_store(o1, (f32x4*)(attn + arow + 4));
      // pack POST-BN values as PV A-frag
      u16x8 pk;
#pragma unroll
      for (int j = 0; j < 4; ++j) pk[j] = f2bf(o0[j]);
#pragma unroll
      for (int j = 0; j < 4; ++j) pk[4 + j] = f2bf(o1[j]);
      bf16x8 pmf = *(bf16x8*)&pk;
      bf16x8 vf[6];
#pragma unroll
      for (int df = 0; df < 6; ++df)
        vf[df] = *(const bf16x8*)(vb + (size_t)(w * HD + df * 16 + lm) * NN
                                   + m0 + ks * 32 + lg * 8);
#pragma unroll
      for (int df = 0; df < 6; ++df)
        oacc[df] = __builtin_amdgcn_mfma_f32_16x16x32_bf16(pmf, vf[df], oacc[df], 0, 0, 0);
    }
    __syncthreads();
  }

  // epilogue: outb rows n0+lg*4+r, col g*96+df*16+lm
#pragma unroll
  for (int df = 0; df < 6; ++df) {
    int col = w * HD + df * 16 + lm;
#pragma unroll
    for (int r = 0; r < 4; ++r) {
      int row = n0 + lg * 4 + r;
      outb[(size_t)(bb * NN + row) * DIM + col] = f2bf(oacc[df][r]);
    }
  }
}

// ---------------- K6: xo = out @ proj_w + proj_b (bf16 MFMA, fp32 out) ----------------
__global__ __launch_bounds__(256) void k_proj(const ushort* __restrict__ outb,
                                              const ushort* __restrict__ wT,
                                              const float* __restrict__ pb,
                                              float* __restrict__ xo) {
  __shared__ ushort As[128][72];
  __shared__ ushort Bs[128][72];
  int m0 = blockIdx.x * 128;
  int j0 = blockIdx.y * 128;
  int t = threadIdx.x;
  int wv = t >> 6, lane = t & 63;
  int wr = (wv >> 1) * 64, wc = (wv & 1) * 64;
  int lm = lane & 15, lg = lane >> 4;
  f32x4 acc[4][4] = {};
  for (int kk = 0; kk < 12; ++kk) {
    int k0 = kk * 64;
    __syncthreads();
    for (int i = t; i < 1024; i += 256) {
      int row = i >> 3;
      int c = (i & 7) * 8;
      *(uint4*)&As[row][c] = *(const uint4*)(outb + (size_t)(m0 + row) * DIM + k0 + c);
      *(uint4*)&Bs[row][c] = *(const uint4*)(wT + (size_t)(j0 + row) * DIM + k0 + c);
    }
    __syncthreads();
#pragma unroll
    for (int ks = 0; ks < 2; ++ks) {
      bf16x8 af[4], bfr[4];
#pragma unroll
      for (int mi = 0; mi < 4; ++mi)
        af[mi] = *(const bf16x8*)&As[wr + mi * 16 + lm][ks * 32 + lg * 8];
#pragma unroll
      for (int ni = 0; ni < 4; ++ni)
        bfr[ni] = *(const bf16x8*)&Bs[wc + ni * 16 + lm][ks * 32 + lg * 8];
#pragma unroll
      for (int mi = 0; mi < 4; ++mi)
#pragma unroll
        for (int ni = 0; ni < 4; ++ni)
          acc[mi][ni] = __builtin_amdgcn_mfma_f32_16x16x32_bf16(af[mi], bfr[ni], acc[mi][ni], 0, 0, 0);
    }
  }
#pragma unroll
  for (int ni = 0; ni < 4; ++ni) {
    int col = j0 + wc + ni * 16 + lm;
    float bias = pb[col];
#pragma unroll
    for (int mi = 0; mi < 4; ++mi)
#pragma unroll
      for (int r = 0; r < 4; ++r) {
        int row = m0 + wr + mi * 16 + lg * 4 + r;
        xo[(size_t)row * DIM + col] = acc[mi][ni][r] + bias;
      }
  }
}

extern "C" void kernel_launch(void* const* d_in, const int* in_sizes, int n_in,
                              void* d_out, int out_size, void* d_ws, size_t ws_size,
                              hipStream_t stream) {
  (void)in_sizes; (void)n_in; (void)out_size;
  const float* x       = (const float*)d_in[0];
  const float* qconv_w = (const float*)d_in[1];
  const float* rw      = (const float*)d_in[2];
  const float* rb      = (const float*)d_in[3];
  const float* gamma   = (const float*)d_in[4];
  const float* beta    = (const float*)d_in[5];
  const float* mean    = (const float*)d_in[6];
  const float* var     = (const float*)d_in[7];
  const float* pw      = (const float*)d_in[8];
  const float* pb      = (const float*)d_in[9];

  float* xo   = (float*)d_out;
  float* attn = xo + (size_t)NB * NN * DIM;  // attn_next output region

  char* ws = (char*)d_ws;
  ushort* q    = (ushort*)(ws);                 // 12,582,912 B
  ushort* qT   = (ushort*)(ws + 12582912);      // 12,582,912 B
  ushort* wT   = (ushort*)(ws + 25165824);      //  1,179,648 B
  ushort* outb = (ushort*)(ws + 26345472);      // 12,582,912 B
  float*  invb = (float*)(ws + 38928384);       //    262,144 B
  float*  psum = (float*)(ws + 39190528);       //  4,194,304 B (max: 64 bh x 16 x 1024)
  ushort* p    = (ushort*)(ws + 43384832);      // full: 134,217,728 B; chunk: 16,777,216 B

  hipLaunchKernelGGL(k_prep_w, dim3(12, 12), dim3(256), 0, stream, pw, wT);
  hipLaunchKernelGGL(k_conv, dim3(NB * NN), dim3(256), 0, stream, x, qconv_w, q);
  hipLaunchKernelGGL(k_transpose_q, dim3(16, 12, NB), dim3(256), 0, stream, q, qT);

  if (ws_size >= 177602560ull) {
    // full mode: all 8 batches at once
    hipLaunchKernelGGL(k_qk, dim3(8, 8, 64), dim3(256), 0, stream, q, p, psum, 0);
    hipLaunchKernelGGL(k_inv, dim3(256), dim3(256), 0, stream, psum, invb, 0);
    hipLaunchKernelGGL(k_mixpv, dim3(512), dim3(512), 0, stream, p, qT, invb,
                       rw, rb, gamma, beta, mean, var, attn, outb, 0, 7, 3);
  } else {
    // chunked fallback: one batch at a time (p slab reused)
    for (int c = 0; c < NB; ++c) {
      hipLaunchKernelGGL(k_qk, dim3(8, 8, 8), dim3(256), 0, stream, q, p, psum, c);
      hipLaunchKernelGGL(k_inv, dim3(32), dim3(256), 0, stream, psum, invb, c);
      hipLaunchKernelGGL(k_mixpv, dim3(64), dim3(512), 0, stream, p, qT, invb,
                         rw, rb, gamma, beta, mean, var, attn, outb, c, 0, 0);
    }
  }
  hipLaunchKernelGGL(k_proj, dim3(64, 6), dim3(256), 0, stream, outb, wT, pb, xo);
}